// Round 15
// baseline (166.911 us; speedup 1.0000x reference)
//
#include <hip/hip_runtime.h>
#include <hip/hip_bf16.h>
#include <math.h>

#define B_  4
#define S_  2048
#define D_  1024
#define NH_ 16
#define HD_ 64

typedef __attribute__((ext_vector_type(8))) short bf16x8;
typedef __attribute__((ext_vector_type(4))) float f32x4;
typedef __attribute__((ext_vector_type(4))) uint  u32x4;

#define VMCNT(n)  asm volatile("s_waitcnt vmcnt(" #n ")" ::: "memory")
#define SCHEDB()  __builtin_amdgcn_sched_barrier(0)
#define BARRIER() __builtin_amdgcn_s_barrier()

__device__ inline ushort f2bf(float f) {
    uint u = __builtin_bit_cast(uint, f);
    uint r = (u + 0x7fffu + ((u >> 16) & 1u)) >> 16;   // RTNE
    return (ushort)r;
}

__device__ inline uint cvt_pk_bf16(float lo, float hi) {
    uint r;
    asm volatile("v_cvt_pk_bf16_f32 %0, %1, %2" : "=v"(r) : "v"(lo), "v"(hi));
    return r;
}

// raw v_exp_f32: args are bounded so no denorm-guard sequence needed
__device__ inline float exp2_raw(float x) {
    float r;
    asm volatile("v_exp_f32 %0, %1" : "=v"(r) : "v"(x));
    return r;
}

#define GLOAD_LDS(gp, lp) \
    __builtin_amdgcn_global_load_lds( \
        (const __attribute__((address_space(1))) uint32_t*)((const void*)(gp)), \
        (__attribute__((address_space(3))) uint32_t*)((void*)(lp)), 16, 0, 0)

// ---------------------------------------------------------------------------
// fused cast: x (nx elems) then Wq,Wk,Wv,Wo (nw each) -> bf16
// ---------------------------------------------------------------------------
__global__ __launch_bounds__(256) void cast_all(const float* __restrict__ x,
                                                const float* __restrict__ w0,
                                                const float* __restrict__ w1,
                                                const float* __restrict__ w2,
                                                const float* __restrict__ w3,
                                                ushort* __restrict__ xb,
                                                ushort* __restrict__ wb,
                                                int nx, int nw) {
    int i = (blockIdx.x * 256 + threadIdx.x) * 4;
    const float* src;
    ushort* dst;
    if (i < nx) {
        src = x + i;
        dst = xb + i;
    } else {
        int j = i - nx;
        int t = j >> 20;              // nw = 1<<20
        int off = j & (nw - 1);
        src = (t == 0 ? w0 : t == 1 ? w1 : t == 2 ? w2 : w3) + off;
        dst = wb + (size_t)t * nw + off;
    }
    float4 f = *reinterpret_cast<const float4*>(src);
    ushort4 o = {f2bf(f.x), f2bf(f.y), f2bf(f.z), f2bf(f.w)};
    *reinterpret_cast<ushort4*>(dst) = o;
}

// ---------------------------------------------------------------------------
// QKV GEMM, 256x256 tile, BK=64, 512 thr (8 waves 2x4), 8-phase schedule with
// counted vmcnt(4)/K-tile (never 0 mid-loop). Double-buffered 128KB LDS,
// XOR bank-swizzle (linear DMA dest, pre-swizzled global source). Per phase:
// 2 prefetch DMAs into regions freed by the previous phase's closing barrier:
//   q0 -> A[mh1] of tile t+1    q1 -> B[nh1] of tile t+1
//   q2 -> B[nh0] of tile t+2    q3 -> A[mh0] of tile t+2
// A-frags held in regs across 2 phases (q0->q2, q1->q3); B-frags across
// (q0->q1, q2->q3): 24 ds_read_b128/tile/wave.
// Outputs: Q scaled by 0.125*log2e; K row-major; V transposed+key-permuted.
// ---------------------------------------------------------------------------
__global__ __launch_bounds__(512, 2) void gemm256_qkv(const ushort* __restrict__ A,
                                                      const ushort* __restrict__ W,
                                                      ushort* __restrict__ Cv,
                                                      int M, int K) {
    __shared__ ushort SH[65536];      // 2 bufs x (A 16384 + B 16384) ushorts

    const int tid = threadIdx.x;
    const int ww = tid >> 6;          // wave 0..7
    const int lam = tid & 63;
    const int wm = ww >> 2;           // 0..1 (M direction, 128 rows each)
    const int wn = ww & 3;            // 0..3 (N direction, 64 cols each)
    const int fr = lam & 15;
    const int fq = lam >> 4;

    const int gx = gridDim.x;                 // 12
    const int nwg = gx * gridDim.y;           // 384
    const int f = blockIdx.y * gx + blockIdx.x;
    const int cpx = nwg >> 3;                 // 48
    const int tileid = (f & 7) * cpx + (f >> 3);
    const int m0 = (tileid / gx) * 256;
    const int n0 = (tileid % gx) * 256;

    f32x4 acc[8][4] = {};

    auto STAGE_A = [&](int mh, uint bufb, int k0) {
#pragma unroll
        for (int l = 0; l < 2; ++l) {
            int group = ww * 2 + l;                       // 0..15
            int base_row = ((group >> 3) << 7) + mh * 64 + (group & 7) * 8;
            int row = base_row + (lam >> 3);
            int kg = (lam & 7) ^ (lam >> 3);
            GLOAD_LDS(&A[(size_t)(m0 + row) * K + k0 + kg * 8],
                      &SH[bufb + base_row * 64 + lam * 8]);
        }
    };
    auto STAGE_B = [&](int nh, uint bufb, int k0) {
#pragma unroll
        for (int l = 0; l < 2; ++l) {
            int gg = ww * 2 + l;
            int base_row = (gg >> 2) * 64 + nh * 32 + (gg & 3) * 8;
            int row = base_row + (lam >> 3);
            int kg = (lam & 7) ^ (lam >> 3);
            GLOAD_LDS(&W[(size_t)(n0 + row) * K + k0 + kg * 8],
                      &SH[bufb + 16384 + base_row * 64 + lam * 8]);
        }
    };
    auto LOAD_AF = [&](bf16x8 (&af)[8], int mh, uint bufb) {
#pragma unroll
        for (int mi = 0; mi < 4; ++mi)
#pragma unroll
            for (int kh = 0; kh < 2; ++kh) {
                int row = wm * 128 + (mh * 4 + mi) * 16 + fr;
                af[mi * 2 + kh] = *reinterpret_cast<const bf16x8*>(
                    &SH[bufb + row * 64 + ((((kh << 2) | fq) ^ (fr & 7)) << 3)]);
            }
    };
    auto LOAD_BF = [&](bf16x8 (&bfv)[4], int nh, uint bufb) {
#pragma unroll
        for (int nn = 0; nn < 2; ++nn)
#pragma unroll
            for (int kh = 0; kh < 2; ++kh) {
                int row = wn * 64 + (nh * 2 + nn) * 16 + fr;
                bfv[nn * 2 + kh] = *reinterpret_cast<const bf16x8*>(
                    &SH[bufb + 16384 + row * 64 + ((((kh << 2) | fq) ^ (fr & 7)) << 3)]);
            }
    };

    bf16x8 af0[8], af1[8], bfv[4];

#define MFMA16(AF, MB, NB)                                                     \
    __builtin_amdgcn_s_setprio(1);                                             \
    _Pragma("unroll")                                                          \
    for (int mi = 0; mi < 4; ++mi)                                             \
        _Pragma("unroll")                                                      \
        for (int nn = 0; nn < 2; ++nn)                                         \
            _Pragma("unroll")                                                  \
            for (int kh = 0; kh < 2; ++kh)                                     \
                acc[(MB) + mi][(NB) + nn] = __builtin_amdgcn_mfma_f32_16x16x32_bf16( \
                    AF[mi * 2 + kh], bfv[nn * 2 + kh], acc[(MB) + mi][(NB) + nn], 0, 0, 0); \
    __builtin_amdgcn_s_setprio(0);

    const int NK = K >> 6;            // 16 K-tiles of 64

    // ---- prologue: tile0 full + tile1 A[0],B[0] ----
    STAGE_A(0, 0, 0); STAGE_A(1, 0, 0);
    STAGE_B(0, 0, 0); STAGE_B(1, 0, 0);
    STAGE_A(0, 32768, 64); STAGE_B(0, 32768, 64);
    VMCNT(4);                         // tile0's 8 loads done
    BARRIER(); SCHEDB();

    for (int t = 0; t < NK; ++t) {
        const uint cur = (t & 1) * 32768u, nxt = 32768u - cur;
        const int k1 = (t + 1) << 6, k2 = (t + 2) << 6;
        // ---- q0 ----
        if (t + 1 < NK) STAGE_A(1, nxt, k1);
        LOAD_AF(af0, 0, cur);
        LOAD_BF(bfv, 0, cur);
        BARRIER();
        MFMA16(af0, 0, 0);
        BARRIER(); SCHEDB();
        // ---- q1 ----
        if (t + 1 < NK) STAGE_B(1, nxt, k1);
        LOAD_AF(af1, 1, cur);
        BARRIER();
        MFMA16(af1, 4, 0);
        BARRIER(); SCHEDB();
        // ---- q2 ----
        if (t + 2 < NK) STAGE_B(0, cur, k2);
        LOAD_BF(bfv, 1, cur);
        BARRIER();
        MFMA16(af0, 0, 2);
        BARRIER(); SCHEDB();
        // ---- q3 ----
        if (t + 2 < NK) STAGE_A(0, cur, k2);
        BARRIER();
        MFMA16(af1, 4, 2);
        BARRIER(); SCHEDB();
        if (t + 2 < NK) { VMCNT(4); }
        else if (t + 1 < NK) { VMCNT(0); }
    }
#undef MFMA16

    // ---- epilogue ----
    const int tensor = n0 >> 10;
    ushort* C = Cv + (size_t)tensor * ((size_t)M * 1024);
    const float scq = (tensor == 0) ? 0.18033688011112042f : 1.0f;  // 0.125*log2e
    const int nb = n0 & 1023;
    if (tensor == 2) {
        // V^T + key-permutation (R10-verified): Vt[(b*16+h)*64+d][2048]
#pragma unroll
        for (int mi = 0; mi < 8; ++mi)
#pragma unroll
            for (int nf = 0; nf < 4; ++nf) {
                int colv = nb + wn * 64 + nf * 16 + fr;
                int hh = colv >> 6, dd = colv & 63;
                int rowb = m0 + wm * 128 + mi * 16 + fq * 4;
                int bb2 = rowb >> 11;
                int s0 = rowb & 2047;
                int c = s0 & 63;
                int spb = (s0 & ~63) | (32 * (c >> 5) + 8 * ((c >> 2) & 3) +
                                        4 * ((c >> 4) & 1));
                size_t base = ((size_t)(bb2 * 16 + hh) * 64 + dd) * 2048 + spb;
#pragma unroll
                for (int r = 0; r < 4; ++r)
                    C[base + r] = f2bf(acc[mi][nf][r]);
            }
    } else {
#pragma unroll
        for (int mi = 0; mi < 8; ++mi)
#pragma unroll
            for (int nf = 0; nf < 4; ++nf) {
                int col = nb + wn * 64 + nf * 16 + fr;
                int rowb = m0 + wm * 128 + mi * 16 + fq * 4;
#pragma unroll
                for (int r = 0; r < 4; ++r)
                    C[(size_t)(rowb + r) * 1024 + col] = f2bf(acc[mi][nf][r] * scq);
            }
    }
}

// ---------------------------------------------------------------------------
// out-proj GEMM (f32 out), 128x128 tile, BK=32, 3-buffer counted vmcnt(4),
// T2 swizzle (conflicts 0). Unchanged from R14.
// ---------------------------------------------------------------------------
__global__ __launch_bounds__(256) void gemm128_out(const ushort* __restrict__ A,
                                                   const ushort* __restrict__ W,
                                                   float* __restrict__ C,
                                                   int M, int Nw, int K) {
    __shared__ ushort SH[3 * 8192];
    const int tid = threadIdx.x;

    const int gx = gridDim.x;
    const int nwg = gx * gridDim.y;
    const int f = blockIdx.y * gx + blockIdx.x;
    const int cpx = nwg >> 3;
    const int tileid = (f & 7) * cpx + (f >> 3);
    const int m0 = (tileid / gx) * 128;
    const int n0 = (tileid % gx) * 128;

    const int lane = tid & 63;
    const int w = tid >> 6;
    const int wr = (w >> 1) * 64;
    const int wc = (w & 1) * 64;
    const int fr = lane & 15;
    const int fq = lane >> 4;

    f32x4 acc[4][4] = {};

    const int srow0 = tid >> 2,          scol0 = (((tid       & 3) ^ ((srow0 >> 1) & 3)) * 8);
    const int srow1 = (tid + 256) >> 2,  scol1 = ((((tid+256) & 3) ^ ((srow1 >> 1) & 3)) * 8);

    auto STAGE = [&](int k0, int bb) {
        GLOAD_LDS(&A[(size_t)(m0 + srow0) * K + k0 + scol0], &SH[bb + tid * 8]);
        GLOAD_LDS(&W[(size_t)(n0 + srow0) * K + k0 + scol0], &SH[bb + 4096 + tid * 8]);
        GLOAD_LDS(&A[(size_t)(m0 + srow1) * K + k0 + scol1], &SH[bb + (tid + 256) * 8]);
        GLOAD_LDS(&W[(size_t)(n0 + srow1) * K + k0 + scol1], &SH[bb + 4096 + (tid + 256) * 8]);
    };
    const int rsw = ((fr >> 1) & 3);
    auto COMPUTE = [&](int bb) {
        bf16x8 af[4], bfv[4];
#pragma unroll
        for (int m = 0; m < 4; ++m)
            af[m] = *reinterpret_cast<const bf16x8*>(
                &SH[bb + (wr + m * 16 + fr) * 32 + ((fq ^ rsw) * 8)]);
#pragma unroll
        for (int n = 0; n < 4; ++n)
            bfv[n] = *reinterpret_cast<const bf16x8*>(
                &SH[bb + 4096 + (wc + n * 16 + fr) * 32 + ((fq ^ rsw) * 8)]);
        __builtin_amdgcn_s_setprio(1);
#pragma unroll
        for (int m = 0; m < 4; ++m)
#pragma unroll
            for (int n = 0; n < 4; ++n)
                acc[m][n] = __builtin_amdgcn_mfma_f32_16x16x32_bf16(af[m], bfv[n], acc[m][n], 0, 0, 0);
        __builtin_amdgcn_s_setprio(0);
    };

    const int NK = K >> 5;
    STAGE(0, 0);
    STAGE(32, 8192);
    VMCNT(4);
    BARRIER(); SCHEDB();

    int ba = 0, bbuf = 8192, bc = 16384;
    for (int t = 0; t < NK; ++t) {
        if (t + 2 < NK) { STAGE((t + 2) * 32, bc); SCHEDB(); }
        COMPUTE(ba);
        if (t + 1 < NK) {
            if (t + 2 < NK) { VMCNT(4); } else { VMCNT(0); }
            BARRIER(); SCHEDB();
        }
        int tmp = ba; ba = bbuf; bbuf = bc; bc = tmp;
    }

#pragma unroll
    for (int m = 0; m < 4; ++m)
#pragma unroll
        for (int n = 0; n < 4; ++n) {
            int col = n0 + wc + n * 16 + fr;
            int rowb = m0 + wr + m * 16 + fq * 4;
#pragma unroll
            for (int r = 0; r < 4; ++r)
                C[(size_t)(rowb + r) * Nw + col] = acc[m][n][r];
        }
}

// ---------------------------------------------------------------------------
// MFMA flash attention (unchanged from R13/R14): all-DMA staging (K + pre-
// transposed Vt), swizzled LDS, VALU-floor softmax (raw v_exp_f32, ones-MFMA
// row sum), 2-buffer 32KB LDS, XCD bh-grouping.
// ---------------------------------------------------------------------------
__global__ __launch_bounds__(256, 4) void attn_mfma(const ushort* __restrict__ Qg,
                                                    const ushort* __restrict__ Kg,
                                                    const ushort* __restrict__ VtG,
                                                    ushort* __restrict__ Yg) {
    __shared__ ushort SH[2 * 8192];   // buf b: K at b*8192, V at b*8192+4096

    const int tid = threadIdx.x;
    const int lane = tid & 63;
    const int w = tid >> 6;
    const int fr = lane & 15;
    const int fq = lane >> 4;

    const int lin = blockIdx.x;
    const int qt = (lin >> 3) & 15;
    const int bh = (lin & 7) * 8 + (lin >> 7);
    const int b = bh >> 4;
    const int h = bh & 15;
    const size_t hbase = (size_t)b * (S_ * D_) + (size_t)h * HD_;
    const size_t vtbase = (size_t)bh * (64 * 2048);
    const int NT = S_ / 64;

    bf16x8 qf[2][2];
#pragma unroll
    for (int m = 0; m < 2; ++m)
#pragma unroll
        for (int kk = 0; kk < 2; ++kk)
            qf[m][kk] = *reinterpret_cast<const bf16x8*>(
                &Qg[hbase + (size_t)(qt * 128 + w * 32 + m * 16 + fr) * D_ + kk * 32 + fq * 8]);

    uint rdoff[2][4];
#pragma unroll
    for (int kk = 0; kk < 2; ++kk)
#pragma unroll
        for (int n = 0; n < 4; ++n)
            rdoff[kk][n] = (uint)((n * 16 + fr) * 64 + 8 * (((kk << 2) + fq) ^ (fr & 7)));

    const int c0i = tid, c1i = tid + 256;
    const int krow0 = c0i >> 3, kslot0 = (c0i & 7) ^ (krow0 & 7);
    const int krow1 = c1i >> 3, kslot1 = (c1i & 7) ^ (krow1 & 7);
    const int vd0 = c0i >> 3, vj0 = ((c0i & 7) ^ (vd0 & 7)) * 8;
    const int vd1 = c1i >> 3, vj1 = ((c1i & 7) ^ (vd1 & 7)) * 8;

    f32x4 oy[2][4] = {};
    f32x4 lacc[2] = {};

    const u32x4 onesu = {0x3F803F80u, 0x3F803F80u, 0x3F803F80u, 0x3F803F80u};
    const bf16x8 onesf = __builtin_bit_cast(bf16x8, onesu);

    auto STAGEK = [&](int kt, int bb) {
        GLOAD_LDS(&Kg[hbase + (size_t)(kt * 64 + krow0) * D_ + kslot0 * 8], &SH[bb + c0i * 8]);
        GLOAD_LDS(&Kg[hbase + (size_t)(kt * 64 + krow1) * D_ + kslot1 * 8], &SH[bb + c1i * 8]);
    };
    auto STAGEV = [&](int kt, int bb) {
        GLOAD_LDS(&VtG[vtbase + (size_t)vd0 * 2048 + kt * 64 + vj0], &SH[bb + 4096 + c0i * 8]);
        GLOAD_LDS(&VtG[vtbase + (size_t)vd1 * 2048 + kt * 64 + vj1], &SH[bb + 4096 + c1i * 8]);
    };
    auto QKT = [&](f32x4 (&sc)[2][4], int bb) {
#pragma unroll
        for (int m = 0; m < 2; ++m)
#pragma unroll
            for (int n = 0; n < 4; ++n) sc[m][n] = f32x4{0.f, 0.f, 0.f, 0.f};
        __builtin_amdgcn_s_setprio(1);
#pragma unroll
        for (int kk = 0; kk < 2; ++kk)
#pragma unroll
            for (int n = 0; n < 4; ++n) {
                bf16x8 kf = *reinterpret_cast<const bf16x8*>(&SH[bb + rdoff[kk][n]]);
                sc[0][n] = __builtin_amdgcn_mfma_f32_16x16x32_bf16(kf, qf[0][kk], sc[0][n], 0, 0, 0);
                sc[1][n] = __builtin_amdgcn_mfma_f32_16x16x32_bf16(kf, qf[1][kk], sc[1][n], 0, 0, 0);
            }
        __builtin_amdgcn_s_setprio(0);
    };
    auto SMPV = [&](f32x4 (&sc)[2][4], int bb) {
        uint pk[2][4][2];
#pragma unroll
        for (int m = 0; m < 2; ++m) {
#pragma unroll
            for (int n = 0; n < 4; ++n)
#pragma unroll
                for (int r = 0; r < 4; ++r)
                    sc[m][n][r] = exp2_raw(sc[m][n][r]);
#pragma unroll
            for (int n = 0; n < 4; ++n) {
                pk[m][n][0] = cvt_pk_bf16(sc[m][n][0], sc[m][n][1]);
                pk[m][n][1] = cvt_pk_bf16(sc[m][n][2], sc[m][n][3]);
            }
        }
        __builtin_amdgcn_s_setprio(1);
#pragma unroll
        for (int kk = 0; kk < 2; ++kk) {
            u32x4 a0 = {pk[0][2 * kk][0], pk[0][2 * kk][1], pk[0][2 * kk + 1][0], pk[0][2 * kk + 1][1]};
            u32x4 a1 = {pk[1][2 * kk][0], pk[1][2 * kk][1], pk[1][2 * kk + 1][0], pk[1][2 * kk + 1][1]};
            bf16x8 pf0 = __builtin_bit_cast(bf16x8, a0);
            bf16x8 pf1 = __builtin_bit_cast(bf16x8, a1);
            lacc[0] = __builtin_amdgcn_mfma_f32_16x16x32_bf16(pf0, onesf, lacc[0], 0, 0, 0);
            lacc[1] = __builtin_amdgcn_mfma_f32_16x16x32_bf16(pf1, onesf, lacc[1], 0, 0, 0);
#pragma unroll
            for (int n = 0; n < 4; ++n) {
                bf16x8 vf = *reinterpret_cast<const bf16x8*>(&SH[bb + 4096 + rdoff[kk][n]]);
                oy[0][n] = __builtin_amdgcn_mfma_f32_16x16x32_bf16(pf0, vf, oy[0][n], 0, 0, 0);
                oy[1][n] = __builtin_amdgcn_mfma_f32_16x16x32_bf16(pf1, vf, oy[1][n], 0, 0, 0);
            }
        }
        __builtin_amdgcn_s_setprio(0);
    };

    STAGEK(0, 0);
    STAGEV(0, 0);
    VMCNT(0);
    BARRIER(); SCHEDB();

    f32x4 sc[2][4];
    for (int t = 0; t < NT; ++t) {
        const int A = (t & 1) * 8192, Bb = 8192 - A;
        if (t + 1 < NT) { STAGEK(t + 1, Bb); STAGEV(t + 1, Bb); SCHEDB(); }
        QKT(sc, A);
        SMPV(sc, A);
        if (t + 1 < NT) { VMCNT(0); BARRIER(); SCHEDB(); }
    }

#pragma unroll
    for (int m = 0; m < 2; ++m) {
#pragma unroll
        for (int r = 0; r < 4; ++r) {
            float inv = 1.0f / lacc[m][r];
            int row = qt * 128 + w * 32 + m * 16 + fq * 4 + r;
#pragma unroll
            for (int n = 0; n < 4; ++n)
                Yg[hbase + (size_t)row * D_ + n * 16 + fr] = f2bf(oy[m][n][r] * inv);
        }
    }
}

// ---------------------------------------------------------------------------
extern "C" void kernel_launch(void* const* d_in, const int* in_sizes, int n_in,
                              void* d_out, int out_size, void* d_ws, size_t ws_size,
                              hipStream_t stream) {
    const float* x  = (const float*)d_in[0];
    const float* Wq = (const float*)d_in[1];
    const float* Wk = (const float*)d_in[2];
    const float* Wv = (const float*)d_in[3];
    const float* Wo = (const float*)d_in[4];
    float* out = (float*)d_out;

    const size_t nx = (size_t)B_ * S_ * D_;
    const size_t nw = (size_t)D_ * D_;

    ushort* xb = (ushort*)d_ws;
    ushort* wb = xb + nx;          // Wq,Wk,Wv,Wo contiguous -> [4096][1024]
    ushort* qb = wb + 4 * nw;      // q, k row-major; v transposed (Vt)
    ushort* kb = qb + nx;
    ushort* vt = kb + nx;
    ushort* yb = vt + nx;

    dim3 blk(256);
    const int ncast = (int)((nx + 4 * nw) / 4 / 256);   // 12288 blocks
    hipLaunchKernelGGL(cast_all, dim3(ncast), blk, 0, stream,
                       x, Wq, Wk, Wv, Wo, xb, wb, (int)nx, (int)nw);

    const int M = B_ * S_;
    dim3 gqkv(3072 / 256, M / 256);           // (12, 32) = 384 blocks, %8==0
    hipLaunchKernelGGL(gemm256_qkv, gqkv, dim3(512), 0, stream, xb, wb, qb, M, D_);

    dim3 gattn(1024);                         // kernel does XCD grouping
    hipLaunchKernelGGL(attn_mfma, gattn, blk, 0, stream, qb, kb, vt, yb);

    dim3 gproj(D_ / 128, M / 128);            // 512 blocks
    hipLaunchKernelGGL(gemm128_out, gproj, blk, 0, stream, yb, wb + 3 * nw, out, M, D_, D_);
}

// Round 16
// 165.840 us; speedup vs baseline: 1.0065x; 1.0065x over previous
//
#include <hip/hip_runtime.h>
#include <hip/hip_bf16.h>
#include <math.h>

#define B_  4
#define S_  2048
#define D_  1024
#define NH_ 16
#define HD_ 64

typedef __attribute__((ext_vector_type(8))) short bf16x8;
typedef __attribute__((ext_vector_type(4))) float f32x4;
typedef __attribute__((ext_vector_type(4))) uint  u32x4;

#define VMCNT(n)  asm volatile("s_waitcnt vmcnt(" #n ")" ::: "memory")
#define SCHEDB()  __builtin_amdgcn_sched_barrier(0)
#define BARRIER() __builtin_amdgcn_s_barrier()

__device__ inline ushort f2bf(float f) {
    uint u = __builtin_bit_cast(uint, f);
    uint r = (u + 0x7fffu + ((u >> 16) & 1u)) >> 16;   // RTNE
    return (ushort)r;
}

__device__ inline uint cvt_pk_bf16(float lo, float hi) {
    uint r;
    asm volatile("v_cvt_pk_bf16_f32 %0, %1, %2" : "=v"(r) : "v"(lo), "v"(hi));
    return r;
}

// raw v_exp_f32: args are bounded so no denorm-guard sequence needed
__device__ inline float exp2_raw(float x) {
    float r;
    asm volatile("v_exp_f32 %0, %1" : "=v"(r) : "v"(x));
    return r;
}

#define GLOAD_LDS(gp, lp) \
    __builtin_amdgcn_global_load_lds( \
        (const __attribute__((address_space(1))) uint32_t*)((const void*)(gp)), \
        (__attribute__((address_space(3))) uint32_t*)((void*)(lp)), 16, 0, 0)

// ---------------------------------------------------------------------------
// fused cast: x (nx elems) then Wq,Wk,Wv,Wo (nw each) -> bf16
// ---------------------------------------------------------------------------
__global__ __launch_bounds__(256) void cast_all(const float* __restrict__ x,
                                                const float* __restrict__ w0,
                                                const float* __restrict__ w1,
                                                const float* __restrict__ w2,
                                                const float* __restrict__ w3,
                                                ushort* __restrict__ xb,
                                                ushort* __restrict__ wb,
                                                int nx, int nw) {
    int i = (blockIdx.x * 256 + threadIdx.x) * 4;
    const float* src;
    ushort* dst;
    if (i < nx) {
        src = x + i;
        dst = xb + i;
    } else {
        int j = i - nx;
        int t = j >> 20;              // nw = 1<<20
        int off = j & (nw - 1);
        src = (t == 0 ? w0 : t == 1 ? w1 : t == 2 ? w2 : w3) + off;
        dst = wb + (size_t)t * nw + off;
    }
    float4 f = *reinterpret_cast<const float4*>(src);
    ushort4 o = {f2bf(f.x), f2bf(f.y), f2bf(f.z), f2bf(f.w)};
    *reinterpret_cast<ushort4*>(dst) = o;
}

// ---------------------------------------------------------------------------
// bf16 MFMA GEMM, 128x128 tile, BK=32, 4 waves. 3-buffer LDS + counted
// vmcnt(4). T2 bank-swizzle (R14, conflicts 0). Balanced grids: qkv 1536
// blocks = 6/CU, proj 512 = 2/CU.
// MODE 0: fused QKV (W rows = 3072): Q scaled by 0.125*log2e; K row-major;
//         V written TRANSPOSED + key-permuted into Vt[bh][64][2048].
// MODE 1: f32 out (out-projection).
// ---------------------------------------------------------------------------
template <int MODE>
__global__ __launch_bounds__(256) void gemm128(const ushort* __restrict__ A,
                                               const ushort* __restrict__ W,
                                               void* __restrict__ Cv,
                                               int M, int Nw, int K) {
    __shared__ ushort SH[3 * 8192];   // buf: A at base, W at base+4096 (16KB each)
    const int tid = threadIdx.x;

    const int gx = gridDim.x;
    const int nwg = gx * gridDim.y;
    const int f = blockIdx.y * gx + blockIdx.x;
    const int cpx = nwg >> 3;
    const int tileid = (f & 7) * cpx + (f >> 3);
    const int m0 = (tileid / gx) * 128;
    const int n0 = (tileid % gx) * 128;

    const int lane = tid & 63;
    const int w = tid >> 6;
    const int wr = (w >> 1) * 64;
    const int wc = (w & 1) * 64;
    const int fr = lane & 15;
    const int fq = lane >> 4;

    f32x4 acc[4][4] = {};

    const int srow0 = tid >> 2,          scol0 = (((tid       & 3) ^ ((srow0 >> 1) & 3)) * 8);
    const int srow1 = (tid + 256) >> 2,  scol1 = ((((tid+256) & 3) ^ ((srow1 >> 1) & 3)) * 8);

    auto STAGE = [&](int k0, int bb) {
        GLOAD_LDS(&A[(size_t)(m0 + srow0) * K + k0 + scol0], &SH[bb + tid * 8]);
        GLOAD_LDS(&W[(size_t)(n0 + srow0) * K + k0 + scol0], &SH[bb + 4096 + tid * 8]);
        GLOAD_LDS(&A[(size_t)(m0 + srow1) * K + k0 + scol1], &SH[bb + (tid + 256) * 8]);
        GLOAD_LDS(&W[(size_t)(n0 + srow1) * K + k0 + scol1], &SH[bb + 4096 + (tid + 256) * 8]);
    };
    const int rsw = ((fr >> 1) & 3);
    auto COMPUTE = [&](int bb) {
        bf16x8 af[4], bfv[4];
#pragma unroll
        for (int m = 0; m < 4; ++m)
            af[m] = *reinterpret_cast<const bf16x8*>(
                &SH[bb + (wr + m * 16 + fr) * 32 + ((fq ^ rsw) * 8)]);
#pragma unroll
        for (int n = 0; n < 4; ++n)
            bfv[n] = *reinterpret_cast<const bf16x8*>(
                &SH[bb + 4096 + (wc + n * 16 + fr) * 32 + ((fq ^ rsw) * 8)]);
        __builtin_amdgcn_s_setprio(1);
#pragma unroll
        for (int m = 0; m < 4; ++m)
#pragma unroll
            for (int n = 0; n < 4; ++n)
                acc[m][n] = __builtin_amdgcn_mfma_f32_16x16x32_bf16(af[m], bfv[n], acc[m][n], 0, 0, 0);
        __builtin_amdgcn_s_setprio(0);
    };

    const int NK = K >> 5;
    STAGE(0, 0);
    STAGE(32, 8192);
    VMCNT(4);
    BARRIER(); SCHEDB();

    int ba = 0, bbuf = 8192, bc = 16384;
    for (int t = 0; t < NK; ++t) {
        if (t + 2 < NK) { STAGE((t + 2) * 32, bc); SCHEDB(); }
        COMPUTE(ba);
        if (t + 1 < NK) {
            if (t + 2 < NK) { VMCNT(4); } else { VMCNT(0); }
            BARRIER(); SCHEDB();
        }
        int tmp = ba; ba = bbuf; bbuf = bc; bc = tmp;
    }

    if (MODE == 0) {
        const int tensor = n0 >> 10;
        ushort* C = (ushort*)Cv + (size_t)tensor * ((size_t)M * 1024);
        const float sc = (tensor == 0) ? 0.18033688011112042f : 1.0f;  // 0.125*log2e
        const int nb = n0 & 1023;
        if (tensor == 2) {
            // V^T + key-permutation (R10-verified): Vt[(b*16+h)*64+d][2048]
#pragma unroll
            for (int m = 0; m < 4; ++m)
#pragma unroll
                for (int n = 0; n < 4; ++n) {
                    int colv = nb + wc + n * 16 + fr;
                    int hh = colv >> 6, dd = colv & 63;
                    int rowb = m0 + wr + m * 16 + fq * 4;
                    int bb2 = rowb >> 11;
                    int s0 = rowb & 2047;
                    int c = s0 & 63;
                    int spb = (s0 & ~63) | (32 * (c >> 5) + 8 * ((c >> 2) & 3) +
                                            4 * ((c >> 4) & 1));
                    ushort* vt = (ushort*)C;
                    size_t base = ((size_t)(bb2 * 16 + hh) * 64 + dd) * 2048 + spb;
#pragma unroll
                    for (int r = 0; r < 4; ++r)
                        vt[base + r] = f2bf(acc[m][n][r]);
                }
        } else {
#pragma unroll
            for (int m = 0; m < 4; ++m)
#pragma unroll
                for (int n = 0; n < 4; ++n) {
                    int col = nb + wc + n * 16 + fr;
                    int rowb = m0 + wr + m * 16 + fq * 4;
#pragma unroll
                    for (int r = 0; r < 4; ++r)
                        C[(size_t)(rowb + r) * 1024 + col] = f2bf(acc[m][n][r] * sc);
                }
        }
    } else {
        float* C = (float*)Cv;
#pragma unroll
        for (int m = 0; m < 4; ++m)
#pragma unroll
            for (int n = 0; n < 4; ++n) {
                int col = n0 + wc + n * 16 + fr;
                int rowb = m0 + wr + m * 16 + fq * 4;
#pragma unroll
                for (int r = 0; r < 4; ++r)
                    C[(size_t)(rowb + r) * Nw + col] = acc[m][n][r];
            }
    }
}

// ---------------------------------------------------------------------------
// MFMA flash attention v13: QBLK = 256 (4 waves x 64 q-rows, grid 512 = 2/CU
// all resident). Per-CU staged K/V bytes and barrier count HALVE vs QBLK=128;
// each DMA covered by a 2x longer compute phase. Two-pass QKT/SMPV (m-pairs)
// caps score liveness at sc[2][4]. Otherwise identical to R13/R14: all-DMA
// staging (K + pre-transposed Vt), swizzled LDS, VALU-floor softmax (raw
// v_exp_f32, ones-MFMA row sum), 2-buffer 32KB LDS, XCD bh-grouping.
// ---------------------------------------------------------------------------
__global__ __launch_bounds__(256, 2) void attn_mfma(const ushort* __restrict__ Qg,
                                                    const ushort* __restrict__ Kg,
                                                    const ushort* __restrict__ VtG,
                                                    ushort* __restrict__ Yg) {
    __shared__ ushort SH[2 * 8192];   // buf b: K at b*8192, V at b*8192+4096

    const int tid = threadIdx.x;
    const int lane = tid & 63;
    const int w = tid >> 6;
    const int fr = lane & 15;
    const int fq = lane >> 4;

    // XCD grouping: all 8 q-tiles (256 rows each) of a bh land on one XCD
    const int lin = blockIdx.x;           // 0..511
    const int qt = (lin >> 3) & 7;
    const int bh = (lin & 7) * 8 + (lin >> 6);
    const int b = bh >> 4;
    const int h = bh & 15;
    const size_t hbase = (size_t)b * (S_ * D_) + (size_t)h * HD_;
    const size_t vtbase = (size_t)bh * (64 * 2048);
    const int NT = S_ / 64;

    // Q fragments (one-time; Q pre-scaled by 0.125*log2e): rows qt*256+w*64+m*16+fr
    bf16x8 qf[4][2];
#pragma unroll
    for (int m = 0; m < 4; ++m)
#pragma unroll
        for (int kk = 0; kk < 2; ++kk)
            qf[m][kk] = *reinterpret_cast<const bf16x8*>(
                &Qg[hbase + (size_t)(qt * 256 + w * 64 + m * 16 + fr) * D_ + kk * 32 + fq * 8]);

    // swizzled LDS read offsets (ushort units)
    uint rdoff[2][4];
#pragma unroll
    for (int kk = 0; kk < 2; ++kk)
#pragma unroll
        for (int n = 0; n < 4; ++n)
            rdoff[kk][n] = (uint)((n * 16 + fr) * 64 + 8 * (((kk << 2) + fq) ^ (fr & 7)));

    // DMA per-thread constants (chunks tid and tid+256)
    const int c0i = tid, c1i = tid + 256;
    const int krow0 = c0i >> 3, kslot0 = (c0i & 7) ^ (krow0 & 7);
    const int krow1 = c1i >> 3, kslot1 = (c1i & 7) ^ (krow1 & 7);
    const int vd0 = c0i >> 3, vj0 = ((c0i & 7) ^ (vd0 & 7)) * 8;
    const int vd1 = c1i >> 3, vj1 = ((c1i & 7) ^ (vd1 & 7)) * 8;

    f32x4 oy[4][4] = {};
    f32x4 lacc[4] = {};

    const u32x4 onesu = {0x3F803F80u, 0x3F803F80u, 0x3F803F80u, 0x3F803F80u};
    const bf16x8 onesf = __builtin_bit_cast(bf16x8, onesu);

    auto STAGEK = [&](int kt, int bb) {
        GLOAD_LDS(&Kg[hbase + (size_t)(kt * 64 + krow0) * D_ + kslot0 * 8], &SH[bb + c0i * 8]);
        GLOAD_LDS(&Kg[hbase + (size_t)(kt * 64 + krow1) * D_ + kslot1 * 8], &SH[bb + c1i * 8]);
    };
    auto STAGEV = [&](int kt, int bb) {
        GLOAD_LDS(&VtG[vtbase + (size_t)vd0 * 2048 + kt * 64 + vj0], &SH[bb + 4096 + c0i * 8]);
        GLOAD_LDS(&VtG[vtbase + (size_t)vd1 * 2048 + kt * 64 + vj1], &SH[bb + 4096 + c1i * 8]);
    };
    // one m-pair (m0b = 0 or 2): QK^T -> exp2 -> pack -> lacc/PV MFMAs
    auto PASS = [&](int m0b, int bb) {
        f32x4 sc[2][4];
#pragma unroll
        for (int m = 0; m < 2; ++m)
#pragma unroll
            for (int n = 0; n < 4; ++n) sc[m][n] = f32x4{0.f, 0.f, 0.f, 0.f};
        __builtin_amdgcn_s_setprio(1);
#pragma unroll
        for (int kk = 0; kk < 2; ++kk)
#pragma unroll
            for (int n = 0; n < 4; ++n) {
                bf16x8 kf = *reinterpret_cast<const bf16x8*>(&SH[bb + rdoff[kk][n]]);
                sc[0][n] = __builtin_amdgcn_mfma_f32_16x16x32_bf16(kf, qf[m0b + 0][kk], sc[0][n], 0, 0, 0);
                sc[1][n] = __builtin_amdgcn_mfma_f32_16x16x32_bf16(kf, qf[m0b + 1][kk], sc[1][n], 0, 0, 0);
            }
        __builtin_amdgcn_s_setprio(0);
        uint pk[2][4][2];
#pragma unroll
        for (int m = 0; m < 2; ++m) {
#pragma unroll
            for (int n = 0; n < 4; ++n)
#pragma unroll
                for (int r = 0; r < 4; ++r)
                    sc[m][n][r] = exp2_raw(sc[m][n][r]);   // no max subtraction
#pragma unroll
            for (int n = 0; n < 4; ++n) {
                pk[m][n][0] = cvt_pk_bf16(sc[m][n][0], sc[m][n][1]);
                pk[m][n][1] = cvt_pk_bf16(sc[m][n][2], sc[m][n][3]);
            }
        }
        __builtin_amdgcn_s_setprio(1);
#pragma unroll
        for (int kk = 0; kk < 2; ++kk) {
            u32x4 a0 = {pk[0][2 * kk][0], pk[0][2 * kk][1], pk[0][2 * kk + 1][0], pk[0][2 * kk + 1][1]};
            u32x4 a1 = {pk[1][2 * kk][0], pk[1][2 * kk][1], pk[1][2 * kk + 1][0], pk[1][2 * kk + 1][1]};
            bf16x8 pf0 = __builtin_bit_cast(bf16x8, a0);
            bf16x8 pf1 = __builtin_bit_cast(bf16x8, a1);
            lacc[m0b + 0] = __builtin_amdgcn_mfma_f32_16x16x32_bf16(pf0, onesf, lacc[m0b + 0], 0, 0, 0);
            lacc[m0b + 1] = __builtin_amdgcn_mfma_f32_16x16x32_bf16(pf1, onesf, lacc[m0b + 1], 0, 0, 0);
#pragma unroll
            for (int n = 0; n < 4; ++n) {
                bf16x8 vf = *reinterpret_cast<const bf16x8*>(&SH[bb + 4096 + rdoff[kk][n]]);
                oy[m0b + 0][n] = __builtin_amdgcn_mfma_f32_16x16x32_bf16(pf0, vf, oy[m0b + 0][n], 0, 0, 0);
                oy[m0b + 1][n] = __builtin_amdgcn_mfma_f32_16x16x32_bf16(pf1, vf, oy[m0b + 1][n], 0, 0, 0);
            }
        }
        __builtin_amdgcn_s_setprio(0);
    };

    // ---- prologue: stage tile 0 ----
    STAGEK(0, 0);
    STAGEV(0, 0);
    VMCNT(0);
    BARRIER(); SCHEDB();

    // ---- main loop: stage t+1 at top, two compute passes, vmcnt(0) at end ----
    for (int t = 0; t < NT; ++t) {
        const int A = (t & 1) * 8192, Bb = 8192 - A;
        if (t + 1 < NT) { STAGEK(t + 1, Bb); STAGEV(t + 1, Bb); SCHEDB(); }
        PASS(0, A);
        PASS(2, A);
        if (t + 1 < NT) { VMCNT(0); BARRIER(); SCHEDB(); }
    }

    // epilogue: l_acc has oy's layout (q = fq*4+r, broadcast over fr) -> no shfl
#pragma unroll
    for (int m = 0; m < 4; ++m) {
#pragma unroll
        for (int r = 0; r < 4; ++r) {
            float inv = 1.0f / lacc[m][r];
            int row = qt * 256 + w * 64 + m * 16 + fq * 4 + r;
#pragma unroll
            for (int n = 0; n < 4; ++n)
                Yg[hbase + (size_t)row * D_ + n * 16 + fr] = f2bf(oy[m][n][r] * inv);
        }
    }
}

// ---------------------------------------------------------------------------
extern "C" void kernel_launch(void* const* d_in, const int* in_sizes, int n_in,
                              void* d_out, int out_size, void* d_ws, size_t ws_size,
                              hipStream_t stream) {
    const float* x  = (const float*)d_in[0];
    const float* Wq = (const float*)d_in[1];
    const float* Wk = (const float*)d_in[2];
    const float* Wv = (const float*)d_in[3];
    const float* Wo = (const float*)d_in[4];
    float* out = (float*)d_out;

    const size_t nx = (size_t)B_ * S_ * D_;
    const size_t nw = (size_t)D_ * D_;

    ushort* xb = (ushort*)d_ws;
    ushort* wb = xb + nx;          // Wq,Wk,Wv,Wo contiguous -> [4096][1024]
    ushort* qb = wb + 4 * nw;      // q, k row-major; v transposed (Vt)
    ushort* kb = qb + nx;
    ushort* vt = kb + nx;
    ushort* yb = vt + nx;

    dim3 blk(256);
    const int ncast = (int)((nx + 4 * nw) / 4 / 256);   // 12288 blocks
    hipLaunchKernelGGL(cast_all, dim3(ncast), blk, 0, stream,
                       x, Wq, Wk, Wv, Wo, xb, wb, (int)nx, (int)nw);

    const int M = B_ * S_;
    dim3 gqkv(3072 / 128, M / 128);           // 1536 blocks = 6/CU, balanced
    hipLaunchKernelGGL((gemm128<0>), gqkv, blk, 0, stream, xb, wb, qb, M, 3072, D_);

    dim3 gattn(512);                          // QBLK=256; kernel does XCD grouping
    hipLaunchKernelGGL(attn_mfma, gattn, blk, 0, stream, qb, kb, vt, yb);

    dim3 gproj(D_ / 128, M / 128);            // 512 blocks = 2/CU
    hipLaunchKernelGGL((gemm128<1>), gproj, blk, 0, stream, yb, wb + 3 * nw, out, M, D_, D_);
}

// Round 18
// 163.992 us; speedup vs baseline: 1.0178x; 1.0113x over previous
//
#include <hip/hip_runtime.h>
#include <hip/hip_bf16.h>
#include <math.h>

#define B_  4
#define S_  2048
#define D_  1024
#define NH_ 16
#define HD_ 64

typedef __attribute__((ext_vector_type(8))) short bf16x8;
typedef __attribute__((ext_vector_type(4))) float f32x4;
typedef __attribute__((ext_vector_type(4))) uint  u32x4;

#define VMCNT(n)  asm volatile("s_waitcnt vmcnt(" #n ")" ::: "memory")
#define SCHEDB()  __builtin_amdgcn_sched_barrier(0)
#define BARRIER() __builtin_amdgcn_s_barrier()

__device__ inline ushort f2bf(float f) {
    uint u = __builtin_bit_cast(uint, f);
    uint r = (u + 0x7fffu + ((u >> 16) & 1u)) >> 16;   // RTNE
    return (ushort)r;
}

__device__ inline uint cvt_pk_bf16(float lo, float hi) {
    uint r;
    asm volatile("v_cvt_pk_bf16_f32 %0, %1, %2" : "=v"(r) : "v"(lo), "v"(hi));
    return r;
}

// raw v_exp_f32: args are bounded so no denorm-guard sequence needed
__device__ inline float exp2_raw(float x) {
    float r;
    asm volatile("v_exp_f32 %0, %1" : "=v"(r) : "v"(x));
    return r;
}

#define GLOAD_LDS(gp, lp) \
    __builtin_amdgcn_global_load_lds( \
        (const __attribute__((address_space(1))) uint32_t*)((const void*)(gp)), \
        (__attribute__((address_space(3))) uint32_t*)((void*)(lp)), 16, 0, 0)

// ---------------------------------------------------------------------------
// fused cast: x (nx elems) then Wq,Wk,Wv,Wo (nw each) -> bf16
// ---------------------------------------------------------------------------
__global__ __launch_bounds__(256) void cast_all(const float* __restrict__ x,
                                                const float* __restrict__ w0,
                                                const float* __restrict__ w1,
                                                const float* __restrict__ w2,
                                                const float* __restrict__ w3,
                                                ushort* __restrict__ xb,
                                                ushort* __restrict__ wb,
                                                int nx, int nw) {
    int i = (blockIdx.x * 256 + threadIdx.x) * 4;
    const float* src;
    ushort* dst;
    if (i < nx) {
        src = x + i;
        dst = xb + i;
    } else {
        int j = i - nx;
        int t = j >> 20;              // nw = 1<<20
        int off = j & (nw - 1);
        src = (t == 0 ? w0 : t == 1 ? w1 : t == 2 ? w2 : w3) + off;
        dst = wb + (size_t)t * nw + off;
    }
    float4 f = *reinterpret_cast<const float4*>(src);
    ushort4 o = {f2bf(f.x), f2bf(f.y), f2bf(f.z), f2bf(f.w)};
    *reinterpret_cast<ushort4*>(dst) = o;
}

// ---------------------------------------------------------------------------
// bf16 MFMA GEMM, 128x128 tile, BK=32, 4 waves. 3-buffer LDS + counted
// vmcnt(4). T2 bank-swizzle (conflicts 0).
// MODE 0: fused QKV (W rows = 3072): Q scaled by 0.125*log2e; K row-major;
//         V transposed+key-permuted into Vt[bh][64][2048] via an LDS
//         transpose so the global write is fully COALESCED. (R17 bug: the
//         s'-slot used global m0 instead of m0&2047, double-counting batch.)
// MODE 1: f32 out (out-projection).
// ---------------------------------------------------------------------------
template <int MODE>
__global__ __launch_bounds__(256) void gemm128(const ushort* __restrict__ A,
                                               const ushort* __restrict__ W,
                                               void* __restrict__ Cv,
                                               int M, int Nw, int K) {
    __shared__ ushort SH[3 * 8192];   // buf: A at base, W at base+4096 (16KB each)
    const int tid = threadIdx.x;

    const int gx = gridDim.x;
    const int nwg = gx * gridDim.y;
    const int f = blockIdx.y * gx + blockIdx.x;
    const int cpx = nwg >> 3;
    const int tileid = (f & 7) * cpx + (f >> 3);
    const int m0 = (tileid / gx) * 128;
    const int n0 = (tileid % gx) * 128;

    const int lane = tid & 63;
    const int w = tid >> 6;
    const int wr = (w >> 1) * 64;
    const int wc = (w & 1) * 64;
    const int fr = lane & 15;
    const int fq = lane >> 4;

    f32x4 acc[4][4] = {};

    const int srow0 = tid >> 2,          scol0 = (((tid       & 3) ^ ((srow0 >> 1) & 3)) * 8);
    const int srow1 = (tid + 256) >> 2,  scol1 = ((((tid+256) & 3) ^ ((srow1 >> 1) & 3)) * 8);

    auto STAGE = [&](int k0, int bb) {
        GLOAD_LDS(&A[(size_t)(m0 + srow0) * K + k0 + scol0], &SH[bb + tid * 8]);
        GLOAD_LDS(&W[(size_t)(n0 + srow0) * K + k0 + scol0], &SH[bb + 4096 + tid * 8]);
        GLOAD_LDS(&A[(size_t)(m0 + srow1) * K + k0 + scol1], &SH[bb + (tid + 256) * 8]);
        GLOAD_LDS(&W[(size_t)(n0 + srow1) * K + k0 + scol1], &SH[bb + 4096 + (tid + 256) * 8]);
    };
    const int rsw = ((fr >> 1) & 3);
    auto COMPUTE = [&](int bb) {
        bf16x8 af[4], bfv[4];
#pragma unroll
        for (int m = 0; m < 4; ++m)
            af[m] = *reinterpret_cast<const bf16x8*>(
                &SH[bb + (wr + m * 16 + fr) * 32 + ((fq ^ rsw) * 8)]);
#pragma unroll
        for (int n = 0; n < 4; ++n)
            bfv[n] = *reinterpret_cast<const bf16x8*>(
                &SH[bb + 4096 + (wc + n * 16 + fr) * 32 + ((fq ^ rsw) * 8)]);
        __builtin_amdgcn_s_setprio(1);
#pragma unroll
        for (int m = 0; m < 4; ++m)
#pragma unroll
            for (int n = 0; n < 4; ++n)
                acc[m][n] = __builtin_amdgcn_mfma_f32_16x16x32_bf16(af[m], bfv[n], acc[m][n], 0, 0, 0);
        __builtin_amdgcn_s_setprio(0);
    };

    const int NK = K >> 5;
    STAGE(0, 0);
    STAGE(32, 8192);
    VMCNT(4);
    BARRIER(); SCHEDB();

    int ba = 0, bbuf = 8192, bc = 16384;
    for (int t = 0; t < NK; ++t) {
        if (t + 2 < NK) { STAGE((t + 2) * 32, bc); SCHEDB(); }
        COMPUTE(ba);
        if (t + 1 < NK) {
            if (t + 2 < NK) { VMCNT(4); } else { VMCNT(0); }
            BARRIER(); SCHEDB();
        }
        int tmp = ba; ba = bbuf; bbuf = bc; bc = tmp;
    }

    if (MODE == 0) {
        const int tensor = n0 >> 10;
        ushort* C = (ushort*)Cv + (size_t)tensor * ((size_t)M * 1024);
        const float sc = (tensor == 0) ? 0.18033688011112042f : 1.0f;  // 0.125*log2e
        const int nb = n0 & 1023;
        if (tensor == 2) {
            // V^T + key-perm sigma, via LDS transpose -> coalesced 16B stores.
            __syncthreads();                      // main-loop LDS reads done
            // step 1: acc -> T[d=0..127][s=0..127], pitch 132
#pragma unroll
            for (int m = 0; m < 4; ++m)
#pragma unroll
                for (int n = 0; n < 4; ++n) {
                    int dloc = wc + n * 16 + fr;
                    int sloc = wr + m * 16 + fq * 4;
                    ushort4 v4 = {f2bf(acc[m][n][0]), f2bf(acc[m][n][1]),
                                  f2bf(acc[m][n][2]), f2bf(acc[m][n][3])};
                    *reinterpret_cast<ushort4*>(&SH[dloc * 132 + sloc]) = v4;
                }
            __syncthreads();
            // step 2: read in inverse-sigma order, write linear (coalesced)
            const int bb2 = m0 >> 11;
            const int s0b = m0 & 2047;            // batch-local s base (R17 bug fix)
            const int hb0 = nb >> 6;
            ushort* vt = (ushort*)C;
#pragma unroll
            for (int t2 = 0; t2 < 8; ++t2) {
                int j = t2 * 256 + tid;
                int row = j >> 4;                 // d-local 0..127
                int ch = j & 15;                  // 16B chunk within 128-s row
                int B64 = (ch & 8) << 3;          // 0 or 64
                int h0 = (2 * ch) & 15, h1 = (2 * ch + 1) & 15;
                int g0 = ((h0 >> 3) & 1) * 8 + (h0 & 1) * 4 + ((h0 >> 2) & 1) * 2 + ((h0 >> 1) & 1);
                int g1 = ((h1 >> 3) & 1) * 8 + (h1 & 1) * 4 + ((h1 >> 2) & 1) * 2 + ((h1 >> 1) & 1);
                ushort4 a4 = *reinterpret_cast<const ushort4*>(&SH[row * 132 + B64 + 4 * g0]);
                ushort4 b4 = *reinterpret_cast<const ushort4*>(&SH[row * 132 + B64 + 4 * g1]);
                int hh = hb0 + (row >> 6), dd = row & 63;
                size_t addr = ((size_t)(bb2 * 16 + hh) * 64 + dd) * 2048 + s0b + ch * 8;
                u32x4 st;
                st[0] = (uint)a4.x | ((uint)a4.y << 16);
                st[1] = (uint)a4.z | ((uint)a4.w << 16);
                st[2] = (uint)b4.x | ((uint)b4.y << 16);
                st[3] = (uint)b4.z | ((uint)b4.w << 16);
                *reinterpret_cast<u32x4*>(&vt[addr]) = st;
            }
        } else {
#pragma unroll
            for (int m = 0; m < 4; ++m)
#pragma unroll
                for (int n = 0; n < 4; ++n) {
                    int col = nb + wc + n * 16 + fr;
                    int rowb = m0 + wr + m * 16 + fq * 4;
#pragma unroll
                    for (int r = 0; r < 4; ++r)
                        C[(size_t)(rowb + r) * 1024 + col] = f2bf(acc[m][n][r] * sc);
                }
        }
    } else {
        float* C = (float*)Cv;
#pragma unroll
        for (int m = 0; m < 4; ++m)
#pragma unroll
            for (int n = 0; n < 4; ++n) {
                int col = n0 + wc + n * 16 + fr;
                int rowb = m0 + wr + m * 16 + fq * 4;
#pragma unroll
                for (int r = 0; r < 4; ++r)
                    C[(size_t)(rowb + r) * Nw + col] = acc[m][n][r];
            }
    }
}

// ---------------------------------------------------------------------------
// MFMA flash attention (R14 exact, QBLK=128): all-DMA staging (K + pre-
// transposed Vt), swizzled LDS, VALU-floor softmax (raw v_exp_f32, ones-MFMA
// row sum), 2-buffer 32KB LDS, XCD bh-grouping.
// ---------------------------------------------------------------------------
__global__ __launch_bounds__(256, 4) void attn_mfma(const ushort* __restrict__ Qg,
                                                    const ushort* __restrict__ Kg,
                                                    const ushort* __restrict__ VtG,
                                                    ushort* __restrict__ Yg) {
    __shared__ ushort SH[2 * 8192];   // buf b: K at b*8192, V at b*8192+4096

    const int tid = threadIdx.x;
    const int lane = tid & 63;
    const int w = tid >> 6;
    const int fr = lane & 15;
    const int fq = lane >> 4;

    const int lin = blockIdx.x;
    const int qt = (lin >> 3) & 15;
    const int bh = (lin & 7) * 8 + (lin >> 7);
    const int b = bh >> 4;
    const int h = bh & 15;
    const size_t hbase = (size_t)b * (S_ * D_) + (size_t)h * HD_;
    const size_t vtbase = (size_t)bh * (64 * 2048);
    const int NT = S_ / 64;

    bf16x8 qf[2][2];
#pragma unroll
    for (int m = 0; m < 2; ++m)
#pragma unroll
        for (int kk = 0; kk < 2; ++kk)
            qf[m][kk] = *reinterpret_cast<const bf16x8*>(
                &Qg[hbase + (size_t)(qt * 128 + w * 32 + m * 16 + fr) * D_ + kk * 32 + fq * 8]);

    uint rdoff[2][4];
#pragma unroll
    for (int kk = 0; kk < 2; ++kk)
#pragma unroll
        for (int n = 0; n < 4; ++n)
            rdoff[kk][n] = (uint)((n * 16 + fr) * 64 + 8 * (((kk << 2) + fq) ^ (fr & 7)));

    const int c0i = tid, c1i = tid + 256;
    const int krow0 = c0i >> 3, kslot0 = (c0i & 7) ^ (krow0 & 7);
    const int krow1 = c1i >> 3, kslot1 = (c1i & 7) ^ (krow1 & 7);
    const int vd0 = c0i >> 3, vj0 = ((c0i & 7) ^ (vd0 & 7)) * 8;
    const int vd1 = c1i >> 3, vj1 = ((c1i & 7) ^ (vd1 & 7)) * 8;

    f32x4 oy[2][4] = {};
    f32x4 lacc[2] = {};

    const u32x4 onesu = {0x3F803F80u, 0x3F803F80u, 0x3F803F80u, 0x3F803F80u};
    const bf16x8 onesf = __builtin_bit_cast(bf16x8, onesu);

    auto STAGEK = [&](int kt, int bb) {
        GLOAD_LDS(&Kg[hbase + (size_t)(kt * 64 + krow0) * D_ + kslot0 * 8], &SH[bb + c0i * 8]);
        GLOAD_LDS(&Kg[hbase + (size_t)(kt * 64 + krow1) * D_ + kslot1 * 8], &SH[bb + c1i * 8]);
    };
    auto STAGEV = [&](int kt, int bb) {
        GLOAD_LDS(&VtG[vtbase + (size_t)vd0 * 2048 + kt * 64 + vj0], &SH[bb + 4096 + c0i * 8]);
        GLOAD_LDS(&VtG[vtbase + (size_t)vd1 * 2048 + kt * 64 + vj1], &SH[bb + 4096 + c1i * 8]);
    };
    auto QKT = [&](f32x4 (&sc)[2][4], int bb) {
#pragma unroll
        for (int m = 0; m < 2; ++m)
#pragma unroll
            for (int n = 0; n < 4; ++n) sc[m][n] = f32x4{0.f, 0.f, 0.f, 0.f};
        __builtin_amdgcn_s_setprio(1);
#pragma unroll
        for (int kk = 0; kk < 2; ++kk)
#pragma unroll
            for (int n = 0; n < 4; ++n) {
                bf16x8 kf = *reinterpret_cast<const bf16x8*>(&SH[bb + rdoff[kk][n]]);
                sc[0][n] = __builtin_amdgcn_mfma_f32_16x16x32_bf16(kf, qf[0][kk], sc[0][n], 0, 0, 0);
                sc[1][n] = __builtin_amdgcn_mfma_f32_16x16x32_bf16(kf, qf[1][kk], sc[1][n], 0, 0, 0);
            }
        __builtin_amdgcn_s_setprio(0);
    };
    auto SMPV = [&](f32x4 (&sc)[2][4], int bb) {
        uint pk[2][4][2];
#pragma unroll
        for (int m = 0; m < 2; ++m) {
#pragma unroll
            for (int n = 0; n < 4; ++n)
#pragma unroll
                for (int r = 0; r < 4; ++r)
                    sc[m][n][r] = exp2_raw(sc[m][n][r]);
#pragma unroll
            for (int n = 0; n < 4; ++n) {
                pk[m][n][0] = cvt_pk_bf16(sc[m][n][0], sc[m][n][1]);
                pk[m][n][1] = cvt_pk_bf16(sc[m][n][2], sc[m][n][3]);
            }
        }
        __builtin_amdgcn_s_setprio(1);
#pragma unroll
        for (int kk = 0; kk < 2; ++kk) {
            u32x4 a0 = {pk[0][2 * kk][0], pk[0][2 * kk][1], pk[0][2 * kk + 1][0], pk[0][2 * kk + 1][1]};
            u32x4 a1 = {pk[1][2 * kk][0], pk[1][2 * kk][1], pk[1][2 * kk + 1][0], pk[1][2 * kk + 1][1]};
            bf16x8 pf0 = __builtin_bit_cast(bf16x8, a0);
            bf16x8 pf1 = __builtin_bit_cast(bf16x8, a1);
            lacc[0] = __builtin_amdgcn_mfma_f32_16x16x32_bf16(pf0, onesf, lacc[0], 0, 0, 0);
            lacc[1] = __builtin_amdgcn_mfma_f32_16x16x32_bf16(pf1, onesf, lacc[1], 0, 0, 0);
#pragma unroll
            for (int n = 0; n < 4; ++n) {
                bf16x8 vf = *reinterpret_cast<const bf16x8*>(&SH[bb + 4096 + rdoff[kk][n]]);
                oy[0][n] = __builtin_amdgcn_mfma_f32_16x16x32_bf16(pf0, vf, oy[0][n], 0, 0, 0);
                oy[1][n] = __builtin_amdgcn_mfma_f32_16x16x32_bf16(pf1, vf, oy[1][n], 0, 0, 0);
            }
        }
        __builtin_amdgcn_s_setprio(0);
    };

    STAGEK(0, 0);
    STAGEV(0, 0);
    VMCNT(0);
    BARRIER(); SCHEDB();

    f32x4 sc[2][4];
    for (int t = 0; t < NT; ++t) {
        const int A = (t & 1) * 8192, Bb = 8192 - A;
        if (t + 1 < NT) { STAGEK(t + 1, Bb); STAGEV(t + 1, Bb); SCHEDB(); }
        QKT(sc, A);
        SMPV(sc, A);
        if (t + 1 < NT) { VMCNT(0); BARRIER(); SCHEDB(); }
    }

#pragma unroll
    for (int m = 0; m < 2; ++m) {
#pragma unroll
        for (int r = 0; r < 4; ++r) {
            float inv = 1.0f / lacc[m][r];
            int row = qt * 128 + w * 32 + m * 16 + fq * 4 + r;
#pragma unroll
            for (int n = 0; n < 4; ++n)
                Yg[hbase + (size_t)row * D_ + n * 16 + fr] = f2bf(oy[m][n][r] * inv);
        }
    }
}

// ---------------------------------------------------------------------------
extern "C" void kernel_launch(void* const* d_in, const int* in_sizes, int n_in,
                              void* d_out, int out_size, void* d_ws, size_t ws_size,
                              hipStream_t stream) {
    const float* x  = (const float*)d_in[0];
    const float* Wq = (const float*)d_in[1];
    const float* Wk = (const float*)d_in[2];
    const float* Wv = (const float*)d_in[3];
    const float* Wo = (const float*)d_in[4];
    float* out = (float*)d_out;

    const size_t nx = (size_t)B_ * S_ * D_;
    const size_t nw = (size_t)D_ * D_;

    ushort* xb = (ushort*)d_ws;
    ushort* wb = xb + nx;          // Wq,Wk,Wv,Wo contiguous -> [4096][1024]
    ushort* qb = wb + 4 * nw;      // q, k row-major; v transposed (Vt)
    ushort* kb = qb + nx;
    ushort* vt = kb + nx;
    ushort* yb = vt + nx;

    dim3 blk(256);
    const int ncast = (int)((nx + 4 * nw) / 4 / 256);   // 12288 blocks
    hipLaunchKernelGGL(cast_all, dim3(ncast), blk, 0, stream,
                       x, Wq, Wk, Wv, Wo, xb, wb, (int)nx, (int)nw);

    const int M = B_ * S_;
    dim3 gqkv(3072 / 128, M / 128);           // 1536 blocks = 6/CU, balanced
    hipLaunchKernelGGL((gemm128<0>), gqkv, blk, 0, stream, xb, wb, qb, M, 3072, D_);

    dim3 gattn(1024);                         // QBLK=128; kernel does XCD grouping
    hipLaunchKernelGGL(attn_mfma, gattn, blk, 0, stream, qb, kb, vt, yb);

    dim3 gproj(D_ / 128, M / 128);            // 512 blocks = 2/CU
    hipLaunchKernelGGL((gemm128<1>), gproj, blk, 0, stream, yb, wb + 3 * nw, out, M, D_, D_);
}

// Round 19
// 162.454 us; speedup vs baseline: 1.0274x; 1.0095x over previous
//
#include <hip/hip_runtime.h>
#include <hip/hip_bf16.h>
#include <math.h>

#define B_  4
#define S_  2048
#define D_  1024
#define NH_ 16
#define HD_ 64

typedef __attribute__((ext_vector_type(8))) short bf16x8;
typedef __attribute__((ext_vector_type(4))) float f32x4;
typedef __attribute__((ext_vector_type(4))) uint  u32x4;

#define VMCNT(n)  asm volatile("s_waitcnt vmcnt(" #n ")" ::: "memory")
#define SCHEDB()  __builtin_amdgcn_sched_barrier(0)
#define BARRIER() __builtin_amdgcn_s_barrier()

__device__ inline ushort f2bf(float f) {
    uint u = __builtin_bit_cast(uint, f);
    uint r = (u + 0x7fffu + ((u >> 16) & 1u)) >> 16;   // RTNE
    return (ushort)r;
}

__device__ inline uint cvt_pk_bf16(float lo, float hi) {
    uint r;
    asm volatile("v_cvt_pk_bf16_f32 %0, %1, %2" : "=v"(r) : "v"(lo), "v"(hi));
    return r;
}

// raw v_exp_f32: args are bounded so no denorm-guard sequence needed
__device__ inline float exp2_raw(float x) {
    float r;
    asm volatile("v_exp_f32 %0, %1" : "=v"(r) : "v"(x));
    return r;
}

#define GLOAD_LDS(gp, lp) \
    __builtin_amdgcn_global_load_lds( \
        (const __attribute__((address_space(1))) uint32_t*)((const void*)(gp)), \
        (__attribute__((address_space(3))) uint32_t*)((void*)(lp)), 16, 0, 0)

// ---------------------------------------------------------------------------
// fused cast: x (nx elems) then Wq,Wk,Wv,Wo (nw each) -> bf16
// ---------------------------------------------------------------------------
__global__ __launch_bounds__(256) void cast_all(const float* __restrict__ x,
                                                const float* __restrict__ w0,
                                                const float* __restrict__ w1,
                                                const float* __restrict__ w2,
                                                const float* __restrict__ w3,
                                                ushort* __restrict__ xb,
                                                ushort* __restrict__ wb,
                                                int nx, int nw) {
    int i = (blockIdx.x * 256 + threadIdx.x) * 4;
    const float* src;
    ushort* dst;
    if (i < nx) {
        src = x + i;
        dst = xb + i;
    } else {
        int j = i - nx;
        int t = j >> 20;              // nw = 1<<20
        int off = j & (nw - 1);
        src = (t == 0 ? w0 : t == 1 ? w1 : t == 2 ? w2 : w3) + off;
        dst = wb + (size_t)t * nw + off;
    }
    float4 f = *reinterpret_cast<const float4*>(src);
    ushort4 o = {f2bf(f.x), f2bf(f.y), f2bf(f.z), f2bf(f.w)};
    *reinterpret_cast<ushort4*>(dst) = o;
}

// ---------------------------------------------------------------------------
// bf16 MFMA GEMM, 128x128 tile, BK=32, 4 waves. 2-BUFFER LDS (32KB, R12
// schedule: stage(t+1) at top, compute(t), vmcnt(0), barrier) -> 5 blocks/CU.
// R13's 3-buffer/48KB variant cost 74 vs 60 us (occupancy loss > prefetch
// depth gain; R14/R18 exonerated swizzle and the Vt epilogue).
// T2 bank-swizzle kept (conflicts ~0).
// MODE 0: fused QKV (W rows = 3072): Q scaled by 0.125*log2e; K row-major;
//         V transposed+key-permuted into Vt[bh][64][2048] via LDS transpose
//         (coalesced stores).
// MODE 1: f32 out (out-projection).
// ---------------------------------------------------------------------------
template <int MODE>
__global__ __launch_bounds__(256) void gemm128(const ushort* __restrict__ A,
                                               const ushort* __restrict__ W,
                                               void* __restrict__ Cv,
                                               int M, int Nw, int K) {
    __shared__ ushort SH[2 * 8192];   // buf: A at base, W at base+4096 (16KB each)
    const int tid = threadIdx.x;

    const int gx = gridDim.x;
    const int nwg = gx * gridDim.y;
    const int f = blockIdx.y * gx + blockIdx.x;
    const int cpx = nwg >> 3;
    const int tileid = (f & 7) * cpx + (f >> 3);
    const int m0 = (tileid / gx) * 128;
    const int n0 = (tileid % gx) * 128;

    const int lane = tid & 63;
    const int w = tid >> 6;
    const int wr = (w >> 1) * 64;
    const int wc = (w & 1) * 64;
    const int fr = lane & 15;
    const int fq = lane >> 4;

    f32x4 acc[4][4] = {};

    const int srow0 = tid >> 2,          scol0 = (((tid       & 3) ^ ((srow0 >> 1) & 3)) * 8);
    const int srow1 = (tid + 256) >> 2,  scol1 = ((((tid+256) & 3) ^ ((srow1 >> 1) & 3)) * 8);

    auto STAGE = [&](int k0, int bb) {
        GLOAD_LDS(&A[(size_t)(m0 + srow0) * K + k0 + scol0], &SH[bb + tid * 8]);
        GLOAD_LDS(&W[(size_t)(n0 + srow0) * K + k0 + scol0], &SH[bb + 4096 + tid * 8]);
        GLOAD_LDS(&A[(size_t)(m0 + srow1) * K + k0 + scol1], &SH[bb + (tid + 256) * 8]);
        GLOAD_LDS(&W[(size_t)(n0 + srow1) * K + k0 + scol1], &SH[bb + 4096 + (tid + 256) * 8]);
    };
    const int rsw = ((fr >> 1) & 3);
    auto COMPUTE = [&](int bb) {
        bf16x8 af[4], bfv[4];
#pragma unroll
        for (int m = 0; m < 4; ++m)
            af[m] = *reinterpret_cast<const bf16x8*>(
                &SH[bb + (wr + m * 16 + fr) * 32 + ((fq ^ rsw) * 8)]);
#pragma unroll
        for (int n = 0; n < 4; ++n)
            bfv[n] = *reinterpret_cast<const bf16x8*>(
                &SH[bb + 4096 + (wc + n * 16 + fr) * 32 + ((fq ^ rsw) * 8)]);
        __builtin_amdgcn_s_setprio(1);
#pragma unroll
        for (int m = 0; m < 4; ++m)
#pragma unroll
            for (int n = 0; n < 4; ++n)
                acc[m][n] = __builtin_amdgcn_mfma_f32_16x16x32_bf16(af[m], bfv[n], acc[m][n], 0, 0, 0);
        __builtin_amdgcn_s_setprio(0);
    };

    const int NK = K >> 5;            // 32
    STAGE(0, 0);
    VMCNT(0);
    BARRIER(); SCHEDB();
    for (int t = 0; t < NK - 1; ++t) {
        const int cur = (t & 1) * 8192;
        STAGE((t + 1) * 32, 8192 - cur);
        SCHEDB();
        COMPUTE(cur);
        VMCNT(0);
        BARRIER(); SCHEDB();
    }
    COMPUTE(((NK - 1) & 1) * 8192);

    if (MODE == 0) {
        const int tensor = n0 >> 10;
        ushort* C = (ushort*)Cv + (size_t)tensor * ((size_t)M * 1024);
        const float sc = (tensor == 0) ? 0.18033688011112042f : 1.0f;  // 0.125*log2e
        const int nb = n0 & 1023;
        if (tensor == 2) {
            // V^T + key-perm sigma, via LDS transpose -> coalesced 16B stores.
            __syncthreads();                      // main-loop LDS reads done
            // step 1: acc -> T[d=0..127][s=0..127], pitch 132 (needs 33.8KB:
            // reuse SH (16KB) is too small -> use two half-tiles sequentially)
#pragma unroll
            for (int half = 0; half < 2; ++half) {
                // half 0: d-local 0..63 ; half 1: d-local 64..127
                if ((wc >> 6) == half) {
#pragma unroll
                    for (int m = 0; m < 4; ++m)
#pragma unroll
                        for (int n = 0; n < 4; ++n) {
                            int dloc = (wc & 63) + n * 16 + fr;   // 0..63
                            int sloc = wr + m * 16 + fq * 4;
                            ushort4 v4 = {f2bf(acc[m][n][0]), f2bf(acc[m][n][1]),
                                          f2bf(acc[m][n][2]), f2bf(acc[m][n][3])};
                            *reinterpret_cast<ushort4*>(&SH[dloc * 132 + sloc]) = v4;
                        }
                }
                __syncthreads();
                // read inverse-sigma, write linear (coalesced); 64 d-rows
                const int bb2 = m0 >> 11;
                const int s0b = m0 & 2047;
                const int hb0 = nb >> 6;
                ushort* vt = (ushort*)C;
#pragma unroll
                for (int t2 = 0; t2 < 4; ++t2) {
                    int j = t2 * 256 + tid;
                    int row = j >> 4;                 // d-local 0..63 within half
                    int ch = j & 15;
                    int B64 = (ch & 8) << 3;
                    int h0 = (2 * ch) & 15, h1 = (2 * ch + 1) & 15;
                    int g0 = ((h0 >> 3) & 1) * 8 + (h0 & 1) * 4 + ((h0 >> 2) & 1) * 2 + ((h0 >> 1) & 1);
                    int g1 = ((h1 >> 3) & 1) * 8 + (h1 & 1) * 4 + ((h1 >> 2) & 1) * 2 + ((h1 >> 1) & 1);
                    ushort4 a4 = *reinterpret_cast<const ushort4*>(&SH[row * 132 + B64 + 4 * g0]);
                    ushort4 b4 = *reinterpret_cast<const ushort4*>(&SH[row * 132 + B64 + 4 * g1]);
                    int drow = half * 64 + row;       // d-local 0..127
                    int hh = hb0 + (drow >> 6), dd = drow & 63;
                    size_t addr = ((size_t)(bb2 * 16 + hh) * 64 + dd) * 2048 + s0b + ch * 8;
                    u32x4 st;
                    st[0] = (uint)a4.x | ((uint)a4.y << 16);
                    st[1] = (uint)a4.z | ((uint)a4.w << 16);
                    st[2] = (uint)b4.x | ((uint)b4.y << 16);
                    st[3] = (uint)b4.z | ((uint)b4.w << 16);
                    *reinterpret_cast<u32x4*>(&vt[addr]) = st;
                }
                if (half == 0) __syncthreads();
            }
        } else {
#pragma unroll
            for (int m = 0; m < 4; ++m)
#pragma unroll
                for (int n = 0; n < 4; ++n) {
                    int col = nb + wc + n * 16 + fr;
                    int rowb = m0 + wr + m * 16 + fq * 4;
#pragma unroll
                    for (int r = 0; r < 4; ++r)
                        C[(size_t)(rowb + r) * 1024 + col] = f2bf(acc[m][n][r] * sc);
                }
        }
    } else {
        float* C = (float*)Cv;
#pragma unroll
        for (int m = 0; m < 4; ++m)
#pragma unroll
            for (int n = 0; n < 4; ++n) {
                int col = n0 + wc + n * 16 + fr;
                int rowb = m0 + wr + m * 16 + fq * 4;
#pragma unroll
                for (int r = 0; r < 4; ++r)
                    C[(size_t)(rowb + r) * Nw + col] = acc[m][n][r];
            }
    }
}

// ---------------------------------------------------------------------------
// MFMA flash attention (R14 exact, QBLK=128): all-DMA staging (K + pre-
// transposed Vt), swizzled LDS, VALU-floor softmax (raw v_exp_f32, ones-MFMA
// row sum), 2-buffer 32KB LDS, XCD bh-grouping.
// ---------------------------------------------------------------------------
__global__ __launch_bounds__(256, 4) void attn_mfma(const ushort* __restrict__ Qg,
                                                    const ushort* __restrict__ Kg,
                                                    const ushort* __restrict__ VtG,
                                                    ushort* __restrict__ Yg) {
    __shared__ ushort SH[2 * 8192];   // buf b: K at b*8192, V at b*8192+4096

    const int tid = threadIdx.x;
    const int lane = tid & 63;
    const int w = tid >> 6;
    const int fr = lane & 15;
    const int fq = lane >> 4;

    const int lin = blockIdx.x;
    const int qt = (lin >> 3) & 15;
    const int bh = (lin & 7) * 8 + (lin >> 7);
    const int b = bh >> 4;
    const int h = bh & 15;
    const size_t hbase = (size_t)b * (S_ * D_) + (size_t)h * HD_;
    const size_t vtbase = (size_t)bh * (64 * 2048);
    const int NT = S_ / 64;

    bf16x8 qf[2][2];
#pragma unroll
    for (int m = 0; m < 2; ++m)
#pragma unroll
        for (int kk = 0; kk < 2; ++kk)
            qf[m][kk] = *reinterpret_cast<const bf16x8*>(
                &Qg[hbase + (size_t)(qt * 128 + w * 32 + m * 16 + fr) * D_ + kk * 32 + fq * 8]);

    uint rdoff[2][4];
#pragma unroll
    for (int kk = 0; kk < 2; ++kk)
#pragma unroll
        for (int n = 0; n < 4; ++n)
            rdoff[kk][n] = (uint)((n * 16 + fr) * 64 + 8 * (((kk << 2) + fq) ^ (fr & 7)));

    const int c0i = tid, c1i = tid + 256;
    const int krow0 = c0i >> 3, kslot0 = (c0i & 7) ^ (krow0 & 7);
    const int krow1 = c1i >> 3, kslot1 = (c1i & 7) ^ (krow1 & 7);
    const int vd0 = c0i >> 3, vj0 = ((c0i & 7) ^ (vd0 & 7)) * 8;
    const int vd1 = c1i >> 3, vj1 = ((c1i & 7) ^ (vd1 & 7)) * 8;

    f32x4 oy[2][4] = {};
    f32x4 lacc[2] = {};

    const u32x4 onesu = {0x3F803F80u, 0x3F803F80u, 0x3F803F80u, 0x3F803F80u};
    const bf16x8 onesf = __builtin_bit_cast(bf16x8, onesu);

    auto STAGEK = [&](int kt, int bb) {
        GLOAD_LDS(&Kg[hbase + (size_t)(kt * 64 + krow0) * D_ + kslot0 * 8], &SH[bb + c0i * 8]);
        GLOAD_LDS(&Kg[hbase + (size_t)(kt * 64 + krow1) * D_ + kslot1 * 8], &SH[bb + c1i * 8]);
    };
    auto STAGEV = [&](int kt, int bb) {
        GLOAD_LDS(&VtG[vtbase + (size_t)vd0 * 2048 + kt * 64 + vj0], &SH[bb + 4096 + c0i * 8]);
        GLOAD_LDS(&VtG[vtbase + (size_t)vd1 * 2048 + kt * 64 + vj1], &SH[bb + 4096 + c1i * 8]);
    };
    auto QKT = [&](f32x4 (&sc)[2][4], int bb) {
#pragma unroll
        for (int m = 0; m < 2; ++m)
#pragma unroll
            for (int n = 0; n < 4; ++n) sc[m][n] = f32x4{0.f, 0.f, 0.f, 0.f};
        __builtin_amdgcn_s_setprio(1);
#pragma unroll
        for (int kk = 0; kk < 2; ++kk)
#pragma unroll
            for (int n = 0; n < 4; ++n) {
                bf16x8 kf = *reinterpret_cast<const bf16x8*>(&SH[bb + rdoff[kk][n]]);
                sc[0][n] = __builtin_amdgcn_mfma_f32_16x16x32_bf16(kf, qf[0][kk], sc[0][n], 0, 0, 0);
                sc[1][n] = __builtin_amdgcn_mfma_f32_16x16x32_bf16(kf, qf[1][kk], sc[1][n], 0, 0, 0);
            }
        __builtin_amdgcn_s_setprio(0);
    };
    auto SMPV = [&](f32x4 (&sc)[2][4], int bb) {
        uint pk[2][4][2];
#pragma unroll
        for (int m = 0; m < 2; ++m) {
#pragma unroll
            for (int n = 0; n < 4; ++n)
#pragma unroll
                for (int r = 0; r < 4; ++r)
                    sc[m][n][r] = exp2_raw(sc[m][n][r]);
#pragma unroll
            for (int n = 0; n < 4; ++n) {
                pk[m][n][0] = cvt_pk_bf16(sc[m][n][0], sc[m][n][1]);
                pk[m][n][1] = cvt_pk_bf16(sc[m][n][2], sc[m][n][3]);
            }
        }
        __builtin_amdgcn_s_setprio(1);
#pragma unroll
        for (int kk = 0; kk < 2; ++kk) {
            u32x4 a0 = {pk[0][2 * kk][0], pk[0][2 * kk][1], pk[0][2 * kk + 1][0], pk[0][2 * kk + 1][1]};
            u32x4 a1 = {pk[1][2 * kk][0], pk[1][2 * kk][1], pk[1][2 * kk + 1][0], pk[1][2 * kk + 1][1]};
            bf16x8 pf0 = __builtin_bit_cast(bf16x8, a0);
            bf16x8 pf1 = __builtin_bit_cast(bf16x8, a1);
            lacc[0] = __builtin_amdgcn_mfma_f32_16x16x32_bf16(pf0, onesf, lacc[0], 0, 0, 0);
            lacc[1] = __builtin_amdgcn_mfma_f32_16x16x32_bf16(pf1, onesf, lacc[1], 0, 0, 0);
#pragma unroll
            for (int n = 0; n < 4; ++n) {
                bf16x8 vf = *reinterpret_cast<const bf16x8*>(&SH[bb + 4096 + rdoff[kk][n]]);
                oy[0][n] = __builtin_amdgcn_mfma_f32_16x16x32_bf16(pf0, vf, oy[0][n], 0, 0, 0);
                oy[1][n] = __builtin_amdgcn_mfma_f32_16x16x32_bf16(pf1, vf, oy[1][n], 0, 0, 0);
            }
        }
        __builtin_amdgcn_s_setprio(0);
    };

    STAGEK(0, 0);
    STAGEV(0, 0);
    VMCNT(0);
    BARRIER(); SCHEDB();

    f32x4 sc[2][4];
    for (int t = 0; t < NT; ++t) {
        const int A = (t & 1) * 8192, Bb = 8192 - A;
        if (t + 1 < NT) { STAGEK(t + 1, Bb); STAGEV(t + 1, Bb); SCHEDB(); }
        QKT(sc, A);
        SMPV(sc, A);
        if (t + 1 < NT) { VMCNT(0); BARRIER(); SCHEDB(); }
    }

#pragma unroll
    for (int m = 0; m < 2; ++m) {
#pragma unroll
        for (int r = 0; r < 4; ++r) {
            float inv = 1.0f / lacc[m][r];
            int row = qt * 128 + w * 32 + m * 16 + fq * 4 + r;
#pragma unroll
            for (int n = 0; n < 4; ++n)
                Yg[hbase + (size_t)row * D_ + n * 16 + fr] = f2bf(oy[m][n][r] * inv);
        }
    }
}

// ---------------------------------------------------------------------------
extern "C" void kernel_launch(void* const* d_in, const int* in_sizes, int n_in,
                              void* d_out, int out_size, void* d_ws, size_t ws_size,
                              hipStream_t stream) {
    const float* x  = (const float*)d_in[0];
    const float* Wq = (const float*)d_in[1];
    const float* Wk = (const float*)d_in[2];
    const float* Wv = (const float*)d_in[3];
    const float* Wo = (const float*)d_in[4];
    float* out = (float*)d_out;

    const size_t nx = (size_t)B_ * S_ * D_;
    const size_t nw = (size_t)D_ * D_;

    ushort* xb = (ushort*)d_ws;
    ushort* wb = xb + nx;          // Wq,Wk,Wv,Wo contiguous -> [4096][1024]
    ushort* qb = wb + 4 * nw;      // q, k row-major; v transposed (Vt)
    ushort* kb = qb + nx;
    ushort* vt = kb + nx;
    ushort* yb = vt + nx;

    dim3 blk(256);
    const int ncast = (int)((nx + 4 * nw) / 4 / 256);   // 12288 blocks
    hipLaunchKernelGGL(cast_all, dim3(ncast), blk, 0, stream,
                       x, Wq, Wk, Wv, Wo, xb, wb, (int)nx, (int)nw);

    const int M = B_ * S_;
    dim3 gqkv(3072 / 128, M / 128);           // 1536 blocks = 6/CU
    hipLaunchKernelGGL((gemm128<0>), gqkv, blk, 0, stream, xb, wb, qb, M, 3072, D_);

    dim3 gattn(1024);                         // QBLK=128; kernel does XCD grouping
    hipLaunchKernelGGL(attn_mfma, gattn, blk, 0, stream, qb, kb, vt, yb);

    dim3 gproj(D_ / 128, M / 128);            // 512 blocks = 2/CU
    hipLaunchKernelGGL((gemm128<1>), gproj, blk, 0, stream, yb, wb + 3 * nw, out, M, D_, D_);
}